// Round 1
// baseline (120.458 us; speedup 1.0000x reference)
//
#include <hip/hip_runtime.h>
#include <math.h>

namespace {
constexpr int N  = 4096;
constexpr int F  = 32;
constexpr int U  = 32;
constexpr int NH = 2;
constexpr int MAXNBR = 1024;   // mean nnz/row ~21, max ~50; 1024 is paranoia margin

__device__ __forceinline__ float leaky(float x) {
    return x >= 0.f ? x : 0.2f * x;
}

__device__ __forceinline__ float wred_max(float v) {
    #pragma unroll
    for (int m = 32; m; m >>= 1) v = fmaxf(v, __shfl_xor(v, m, 64));
    return v;
}
__device__ __forceinline__ float wred_sum(float v) {
    #pragma unroll
    for (int m = 32; m; m >>= 1) v += __shfl_xor(v, m, 64);
    return v;
}

// X = H @ W per head (both real & imag), plus the 4 attention-logit vectors
// sr/nr (from Xr·a1, Xr·a2) and si/ni (from Xi·a1, Xi·a2).
__global__ __launch_bounds__(256) void proj_kernel(
    const float* __restrict__ Hr, const float* __restrict__ Hi,
    const float* __restrict__ W,  const float* __restrict__ a1,
    const float* __restrict__ a2,
    float* __restrict__ Xr, float* __restrict__ Xi,
    float* __restrict__ sr, float* __restrict__ si,
    float* __restrict__ nr, float* __restrict__ ni)
{
    __shared__ float sW[NH * F * U];   // 8 KB
    __shared__ float sH[2][8][F];      // 2 KB
    const int t = threadIdx.x;
    for (int k = t; k < NH * F * U; k += 256) sW[k] = W[k];
    const int row0 = blockIdx.x * 8;
    {
        const int r = t >> 5, f = t & 31;   // 256 threads = 8 rows x 32 f
        sH[0][r][f] = Hr[(row0 + r) * F + f];
        sH[1][r][f] = Hi[(row0 + r) * F + f];
    }
    __syncthreads();

    const int r = t >> 5, u = t & 31;
    const int n = row0 + r;
    float xr[NH] = {0.f, 0.f}, xi[NH] = {0.f, 0.f};
    #pragma unroll
    for (int h = 0; h < NH; ++h) {
        #pragma unroll
        for (int f = 0; f < F; ++f) {
            const float w = sW[h * F * U + f * U + u];   // u-consecutive: conflict-free
            xr[h] += sH[0][r][f] * w;                    // broadcast read
            xi[h] += sH[1][r][f] * w;
        }
    }
    #pragma unroll
    for (int h = 0; h < NH; ++h) {
        Xr[(h * N + n) * U + u] = xr[h];
        Xi[(h * N + n) * U + u] = xi[h];
    }
    #pragma unroll
    for (int h = 0; h < NH; ++h) {
        const float av1 = a1[h * U + u], av2 = a2[h * U + u];
        float vsr = xr[h] * av1, vnr = xr[h] * av2;
        float vsi = xi[h] * av1, vni = xi[h] * av2;
        #pragma unroll
        for (int m = 16; m; m >>= 1) {   // width-32 butterfly: reduce over u
            vsr += __shfl_xor(vsr, m, 32);
            vnr += __shfl_xor(vnr, m, 32);
            vsi += __shfl_xor(vsi, m, 32);
            vni += __shfl_xor(vni, m, 32);
        }
        if (u == 0) {
            sr[h * N + n] = vsr;
            nr[h * N + n] = vnr;
            si[h * N + n] = vsi;
            ni[h * N + n] = vni;
        }
    }
}

// One block per row i. Fuses both heads + real/imag so the A row (16 KB)
// is read exactly once. Masked entries (A==0) contribute exp(-1e10-m)==0
// in fp32 (diagonal is always unmasked, so max is from an unmasked entry)
// -> skip them entirely.
__global__ __launch_bounds__(256) void attn_kernel(
    const float* __restrict__ A,
    const float* __restrict__ Xr, const float* __restrict__ Xi,
    const float* __restrict__ sr, const float* __restrict__ si,
    const float* __restrict__ nr, const float* __restrict__ ni,
    float* __restrict__ out)
{
    __shared__ int   s_nbr[MAXNBR];      // 4 KB
    __shared__ float s_e[4][MAXNBR];     // 16 KB: logits, then exp-weights
    __shared__ float s_pmax[4][4];
    __shared__ float s_psum[4][4];
    __shared__ float s_accr[256];        // 1 KB
    __shared__ float s_acci[256];        // 1 KB
    __shared__ int   s_cnt;

    const int i = blockIdx.x;
    const int t = threadIdx.x;
    const int lane = t & 63, wv = t >> 6;

    if (t == 0) s_cnt = 0;
    __syncthreads();

    // phase 1: compact nonzero columns of A row i (A values are exactly 0/1)
    const float4* Arow = (const float4*)(A + (size_t)i * N);
    #pragma unroll
    for (int k = t; k < N / 4; k += 256) {
        const float4 v = Arow[k];
        if (v.x != 0.f) { int p = atomicAdd(&s_cnt, 1); if (p < MAXNBR) s_nbr[p] = 4 * k + 0; }
        if (v.y != 0.f) { int p = atomicAdd(&s_cnt, 1); if (p < MAXNBR) s_nbr[p] = 4 * k + 1; }
        if (v.z != 0.f) { int p = atomicAdd(&s_cnt, 1); if (p < MAXNBR) s_nbr[p] = 4 * k + 2; }
        if (v.w != 0.f) { int p = atomicAdd(&s_cnt, 1); if (p < MAXNBR) s_nbr[p] = 4 * k + 3; }
    }
    __syncthreads();
    const int cnt = min(s_cnt, MAXNBR);

    float sri[NH], sii[NH];
    #pragma unroll
    for (int h = 0; h < NH; ++h) { sri[h] = sr[h * N + i]; sii[h] = si[h * N + i]; }

    // phase 2a: logits + per-thread max   (v index: 2*h+0 = real(E1), 2*h+1 = imag(E2))
    float m[4] = {-INFINITY, -INFINITY, -INFINITY, -INFINITY};
    for (int j = t; j < cnt; j += 256) {
        const int nj = s_nbr[j];
        #pragma unroll
        for (int h = 0; h < NH; ++h) {
            const float e1 = leaky(sri[h] + nr[h * N + nj]);
            const float e2 = leaky(sii[h] + ni[h * N + nj]);
            s_e[2 * h + 0][j] = e1;
            s_e[2 * h + 1][j] = e2;
            m[2 * h + 0] = fmaxf(m[2 * h + 0], e1);
            m[2 * h + 1] = fmaxf(m[2 * h + 1], e2);
        }
    }
    #pragma unroll
    for (int v = 0; v < 4; ++v) {
        const float wm = wred_max(m[v]);
        if (lane == 0) s_pmax[wv][v] = wm;
    }
    __syncthreads();
    float mx[4], sum[4];
    #pragma unroll
    for (int v = 0; v < 4; ++v) {
        mx[v] = fmaxf(fmaxf(s_pmax[0][v], s_pmax[1][v]),
                      fmaxf(s_pmax[2][v], s_pmax[3][v]));
        sum[v] = 0.f;
    }

    // phase 2b: exp + sum
    for (int j = t; j < cnt; j += 256) {
        #pragma unroll
        for (int v = 0; v < 4; ++v) {
            const float w = __expf(s_e[v][j] - mx[v]);
            s_e[v][j] = w;
            sum[v] += w;
        }
    }
    #pragma unroll
    for (int v = 0; v < 4; ++v) {
        const float ws = wred_sum(sum[v]);
        if (lane == 0) s_psum[wv][v] = ws;
    }
    __syncthreads();
    float rinv[4];
    #pragma unroll
    for (int v = 0; v < 4; ++v)
        rinv[v] = 1.f / (s_psum[0][v] + s_psum[1][v] + s_psum[2][v] + s_psum[3][v]);

    // phase 3: weighted gather.  t = (g:2)(h:1)(u:5); g strides the neighbor list.
    const int g = t >> 6, h = (t >> 5) & 1, u = t & 31;
    const float r1 = rinv[2 * h + 0], r2 = rinv[2 * h + 1];
    float accr = 0.f, acci = 0.f;
    for (int j = g; j < cnt; j += 4) {
        const int nj = s_nbr[j];
        const float w1 = s_e[2 * h + 0][j] * r1;   // alpha1
        const float w2 = s_e[2 * h + 1][j] * r2;   // alpha2
        const float xr = Xr[(h * N + nj) * U + u];
        const float xi = Xi[(h * N + nj) * U + u];
        accr += w1 * xr - w2 * xi;
        acci += w1 * xi + w2 * xr;
    }
    s_accr[t] = accr;
    s_acci[t] = acci;
    __syncthreads();
    if (g == 0) {
        const float vr = s_accr[t] + s_accr[t + 64] + s_accr[t + 128] + s_accr[t + 192];
        const float vi = s_acci[t] + s_acci[t + 64] + s_acci[t + 128] + s_acci[t + 192];
        // out_r [N, NH*U] then out_i [N, NH*U]; t in [0,64) -> coalesced 256 B rows
        out[(size_t)i * (NH * U) + h * U + u] = vr;
        out[(size_t)N * NH * U + (size_t)i * (NH * U) + h * U + u] = vi;
    }
}
} // anonymous namespace

extern "C" void kernel_launch(void* const* d_in, const int* in_sizes, int n_in,
                              void* d_out, int out_size, void* d_ws, size_t ws_size,
                              hipStream_t stream) {
    (void)in_sizes; (void)n_in; (void)out_size; (void)ws_size;
    const float* Hr = (const float*)d_in[0];
    const float* Hi = (const float*)d_in[1];
    const float* A  = (const float*)d_in[2];
    const float* W  = (const float*)d_in[3];
    const float* a1 = (const float*)d_in[4];
    const float* a2 = (const float*)d_in[5];
    float* out = (float*)d_out;

    float* ws = (float*)d_ws;            // 2.2 MB used; rewritten fully each call
    float* Xr = ws;                      // NH*N*U
    float* Xi = Xr + NH * N * U;         // NH*N*U
    float* sr = Xi + NH * N * U;         // NH*N
    float* si = sr + NH * N;
    float* nr = si + NH * N;
    float* ni = nr + NH * N;

    proj_kernel<<<N / 8, 256, 0, stream>>>(Hr, Hi, W, a1, a2, Xr, Xi, sr, si, nr, ni);
    attn_kernel<<<N, 256, 0, stream>>>(A, Xr, Xi, sr, si, nr, ni, out);
}